// Round 9
// baseline (514.714 us; speedup 1.0000x reference)
//
#include <hip/hip_runtime.h>

#define DIM 256
#define N_REL 8
#define NBLK 256     // blocks in build/scatter passes
#define NBINS 512    // MSD bins: [g:1][dst_high:8]

typedef __attribute__((ext_vector_type(8))) short short8_t;
typedef __attribute__((ext_vector_type(4))) float float4_t;

// ---------------- bf16 helpers (manual, RNE) ----------------
__device__ inline unsigned short f2bf(float f) {
    unsigned u = __float_as_uint(f);
    u += 0x7FFFu + ((u >> 16) & 1u);
    return (unsigned short)(u >> 16);
}
__device__ inline float bf2f(unsigned short h) {
    return __uint_as_float(((unsigned)h) << 16);
}

// ---------------------------------------------------------------------------
// prep megakernel: {cast x->bf16 | transpose W0 | transpose W1}.
// ---------------------------------------------------------------------------
__global__ __launch_bounds__(256) void prep_mega(
    const float* __restrict__ x, unsigned short* __restrict__ xb, int n4,
    const float* __restrict__ W0, unsigned short* __restrict__ Wt0,
    const float* __restrict__ W1, unsigned short* __restrict__ Wt1,
    int nCast, int nW)
{
    __shared__ float tile[32][33];
    const int b = blockIdx.x;
    const int t = threadIdx.x;
    if (b < nCast) {
        const int i = b * 256 + t;
        if (i < n4) {
            const float4 v = ((const float4*)x)[i];
            ushort4 o;
            o.x = f2bf(v.x); o.y = f2bf(v.y); o.z = f2bf(v.z); o.w = f2bf(v.w);
            ((ushort4*)xb)[i] = o;
        }
    } else {
        const int wi = b - nCast;
        const float* W = (wi < nW) ? W0 : W1;
        unsigned short* Wt = (wi < nW) ? Wt0 : Wt1;
        const int bb = (wi < nW) ? wi : wi - nW;
        const int rel = bb >> 6;
        const int bx = bb & 7, by = (bb >> 3) & 7;
        const int i0 = bx * 32, o0 = by * 32;
        const int tx = t & 31, ty = t >> 5;          // (32, 8)
        const float* Wr = W + (size_t)rel * DIM * DIM;
        unsigned short* Wtr = Wt + (size_t)rel * DIM * DIM;
#pragma unroll
        for (int j = 0; j < 4; j++)
            tile[ty + 8 * j][tx] = Wr[(size_t)(i0 + ty + 8 * j) * DIM + o0 + tx];
        __syncthreads();
#pragma unroll
        for (int j = 0; j < 4; j++)
            Wtr[(size_t)(o0 + ty + 8 * j) * DIM + i0 + tx] =
                f2bf(tile[tx][ty + 8 * j]);
    }
}

// ---------------------------------------------------------------------------
// Atomic-free CSR build, R14: sort by (g, dst) where g = et>>2 (rel group).
// key u64 = [g:1 @bit48][dst:16 @bit32][et:16 @bit16][src:16 @bit0].
// MSD bin = (v>>40) & 0x1FF = [g][dst_high]. 512 bins.
// e64a/e64b transients alias the ybuf region (dead before first GEMM).
// ---------------------------------------------------------------------------
__global__ __launch_bounds__(256) void build_keys_hist(
    const int* __restrict__ src, const int* __restrict__ dst,
    const int* __restrict__ et, int E,
    unsigned long long* __restrict__ e0, int* __restrict__ hist)
{
    __shared__ int lh[NBINS];
    const int t = threadIdx.x, b = blockIdx.x;
    lh[t] = 0; lh[t + 256] = 0;
    __syncthreads();
    const int chunk = (E + NBLK - 1) / NBLK;
    const int lo = b * chunk, hi = min(lo + chunk, E);
    for (int i = lo + t; i < hi; i += 256) {
        const unsigned d = (unsigned)dst[i];
        const unsigned e = (unsigned)et[i];
        const unsigned g = e >> 2;
        e0[i] = ((unsigned long long)((g << 16) | d) << 32) |
                ((e << 16) | (unsigned)src[i]);
        atomicAdd(&lh[(g << 8) | (d >> 8)], 1);     // LDS atomic
    }
    __syncthreads();
    hist[t * NBLK + b] = lh[t];
    hist[(t + 256) * NBLK + b] = lh[t + 256];
}

// Generic exclusive-scan pair (nb <= 256). outArr may alias a.
__global__ __launch_bounds__(256) void scan_g_blocksums(
    const int* __restrict__ a, int n, int* __restrict__ bsum)
{
    __shared__ int red[256];
    const int t = threadIdx.x;
    const int base = blockIdx.x * 1024 + t * 4;
    int s = 0;
#pragma unroll
    for (int j = 0; j < 4; j++) {
        const int i = base + j;
        if (i < n) s += a[i];
    }
    red[t] = s;
    __syncthreads();
#pragma unroll
    for (int off = 128; off > 0; off >>= 1) {
        if (t < off) red[t] += red[t + off];
        __syncthreads();
    }
    if (t == 0) bsum[blockIdx.x] = red[0];
}

__global__ __launch_bounds__(256) void scan_g_write(
    const int* __restrict__ a, int n, const int* __restrict__ bsum, int nb,
    int* __restrict__ outArr, int* __restrict__ totalSlot)
{
    __shared__ int sb[256];
    __shared__ int sh[256];
    const int t = threadIdx.x;
    sb[t] = (t < nb) ? bsum[t] : 0;
    __syncthreads();
    for (int off = 1; off < 256; off <<= 1) {
        const int v = sb[t] + ((t >= off) ? sb[t - off] : 0);
        __syncthreads();
        sb[t] = v;
        __syncthreads();
    }
    const int run0 = (blockIdx.x == 0) ? 0 : sb[blockIdx.x - 1];
    const int total = sb[nb - 1];

    const int base = blockIdx.x * 1024 + t * 4;
    int v[4];
#pragma unroll
    for (int j = 0; j < 4; j++) {
        const int i = base + j;
        v[j] = (i < n) ? a[i] : 0;
    }
    sh[t] = v[0] + v[1] + v[2] + v[3];
    __syncthreads();
    for (int off = 1; off < 256; off <<= 1) {
        const int add = (t >= off) ? sh[t - off] : 0;
        __syncthreads();
        sh[t] += add;
        __syncthreads();
    }
    int run = run0 + ((t == 0) ? 0 : sh[t - 1]);
#pragma unroll
    for (int j = 0; j < 4; j++) {
        const int i = base + j;
        if (i < n) outArr[i] = run;
        run += v[j];
    }
    if (totalSlot && (int)blockIdx.x == nb - 1 && t == 255) *totalSlot = total;
}

// Pass B: scatter into 512 (g,dst_high) buckets. Order within bucket varies
// run-to-run (LDS-atomic rank) -- safe: per-dst sums are fp64 (R11).
__global__ __launch_bounds__(256) void scatter_pass1(
    const unsigned long long* __restrict__ e0, int E,
    const int* __restrict__ histx, unsigned long long* __restrict__ e1)
{
    __shared__ int lbase[NBINS];
    __shared__ int lrun[NBINS];
    const int t = threadIdx.x, b = blockIdx.x;
    lbase[t] = histx[t * NBLK + b];
    lbase[t + 256] = histx[(t + 256) * NBLK + b];
    lrun[t] = 0; lrun[t + 256] = 0;
    __syncthreads();
    const int chunk = (E + NBLK - 1) / NBLK;
    const int lo = b * chunk, hi = min(lo + chunk, E);
    for (int i = lo + t; i < hi; i += 256) {
        const unsigned long long v = e0[i];
        const int bin = (int)(v >> 40) & 0x1FF;
        const int pos = lbase[bin] + atomicAdd(&lrun[bin], 1);
        e1[pos] = v;
    }
}

// Pass C: one block per bucket; LDS counting sort on dst low byte.
// Writes final ep + cnt2[g*M + dst] (single writer per (g,dst)).
__global__ __launch_bounds__(256) void bucket_sort(
    const unsigned long long* __restrict__ e1, int E,
    const int* __restrict__ histx,
    unsigned* __restrict__ ep, int* __restrict__ cnt2, int M)
{
    __shared__ int lh[256], lincl[256], lexcl[256], lrun[256];
    const int t = threadIdx.x;
    const int h = blockIdx.x;                 // bin = [g][dst_high]
    const int start = histx[h * NBLK];
    const int end = (h == NBINS - 1) ? E : histx[(h + 1) * NBLK];
    if (end <= start) return;                 // uniform across block
    lh[t] = 0;
    __syncthreads();
    for (int i = start + t; i < end; i += 256)
        atomicAdd(&lh[(int)(e1[i] >> 32) & 0xFF], 1);
    __syncthreads();
    const int v = lh[t];
    lincl[t] = v;
    __syncthreads();
    for (int off = 1; off < 256; off <<= 1) {
        const int add = (t >= off) ? lincl[t - off] : 0;
        __syncthreads();
        lincl[t] += add;
        __syncthreads();
    }
    lexcl[t] = lincl[t] - v;
    lrun[t] = 0;
    if (v > 0) {
        const int g = h >> 8;
        const int d = ((h & 0xFF) << 8) | t;  // global dst
        cnt2[g * M + d] = v;
    }
    __syncthreads();
    for (int i = start + t; i < end; i += 256) {
        const unsigned long long x = e1[i];
        const int low = (int)(x >> 32) & 0xFF;
        const int pos = lexcl[low] + atomicAdd(&lrun[low], 1);
        ep[start + pos] = (unsigned)(x & 0xFFFFFFFFu);
    }
}

// ---------------------------------------------------------------------------
// Yg[rel'][M][256] = relu(Xb @ W[4g+rel'] + bias) bf16, rel' in [0,4).
// R14: 4-rel pass writing a 102.4MB plane buffer (L3-resident; consumed by
// the immediately-following aggregate pass, then overwritten by the next
// GEMM pass -> HBM writeback mostly absorbed).
// Structure: R11-verified 2-buffer vmcnt(4), gload_lds w16, XOR swizzle.
// 1-D grid, octet swizzle: rt = (gg>>3)*8 | xcd; 8 combos (2 ntile x 4 rel).
// ---------------------------------------------------------------------------
__global__ __launch_bounds__(256) void gemm_mfma_bias_relu(
    const unsigned short* __restrict__ Xb,    // [M][256]
    const unsigned short* __restrict__ Wtb,   // [4][256out][256in] (group base)
    const float* __restrict__ bias,           // [256]
    unsigned short* __restrict__ Yg, int M, int Rtiles)
{
    __shared__ __align__(16) short smem[16384];   // 32 KiB, 2 buffers

    const unsigned L = blockIdx.x;
    const int xcd = L & 7;
    const unsigned gg = L >> 3;
    const int combo = gg & 7;                 // (ntile, rel')
    const int rt = (int)((gg >> 3) << 3) | xcd;
    if (rt >= Rtiles) return;
    const int m0 = rt * 128;
    const int n0 = (combo & 1) * 128;
    const int rel = combo >> 1;               // 0..3

    const unsigned short* Wt = Wtb + (size_t)rel * DIM * DIM;
    unsigned short* Y = Yg + (size_t)rel * M * DIM;

    const int t = threadIdx.x;
    const int lane = t & 63;
    const int w = t >> 6;
    const int wr = w & 1, wc = w >> 1;
    const int r = lane & 15, q = lane >> 4;

    const int sl = lane & 3;
    const int rsub = lane >> 2;
    const unsigned short* gA[2];
    const unsigned short* gB[2];
#pragma unroll
    for (int h = 0; h < 2; h++) {
        const int row = h * 64 + w * 16 + rsub;
        const int gseg = sl ^ ((row >> 1) & 3);          // pre-swizzled source
        gA[h] = Xb + (size_t)(m0 + row) * DIM + gseg * 8;
        gB[h] = Wt + (size_t)(n0 + row) * DIM + gseg * 8;
    }

    const int swz = (q ^ ((r >> 1) & 3)) * 8;
    int offA[4], offB[4];
#pragma unroll
    for (int mi = 0; mi < 4; mi++)
        offA[mi] = (wr * 64 + mi * 16 + r) * 32 + swz;
#pragma unroll
    for (int ni = 0; ni < 4; ni++)
        offB[ni] = (wc * 64 + ni * 16 + r) * 32 + swz;

    float4_t acc[4][4];
#pragma unroll
    for (int i = 0; i < 4; i++)
#pragma unroll
        for (int j = 0; j < 4; j++) {
            float4_t z = {0.f, 0.f, 0.f, 0.f};
            acc[i][j] = z;
        }

#define STAGE(ks, bsel)                                                         \
    {                                                                           \
        const int k0_ = (ks) * 32;                                              \
        short* Ad_ = smem + ((bsel) ? 8192 : 0);                                \
        short* Bd_ = Ad_ + 4096;                                                \
        _Pragma("unroll")                                                       \
        for (int h = 0; h < 2; h++) {                                           \
            __builtin_amdgcn_global_load_lds(                                   \
                (const __attribute__((address_space(1))) unsigned int*)(gA[h] + k0_), \
                (__attribute__((address_space(3))) unsigned int*)(Ad_ + h * 2048 + w * 512), \
                16, 0, 0);                                                      \
            __builtin_amdgcn_global_load_lds(                                   \
                (const __attribute__((address_space(1))) unsigned int*)(gB[h] + k0_), \
                (__attribute__((address_space(3))) unsigned int*)(Bd_ + h * 2048 + w * 512), \
                16, 0, 0);                                                      \
        }                                                                       \
    }

    STAGE(0, 0);
#pragma unroll 1
    for (int ks = 0; ks < 8; ks++) {
        const int cur = ks & 1;
        if (ks < 7) {
            STAGE(ks + 1, cur ^ 1);
            asm volatile("s_waitcnt vmcnt(4)" ::: "memory");
        } else {
            asm volatile("s_waitcnt vmcnt(0)" ::: "memory");
        }
        asm volatile("s_barrier" ::: "memory");

        const short* As_b = smem + (cur ? 8192 : 0);
        const short* Bs_b = As_b + 4096;
        short8_t af[4], bf[4];
#pragma unroll
        for (int mi = 0; mi < 4; mi++)
            af[mi] = *(const short8_t*)&As_b[offA[mi]];
#pragma unroll
        for (int ni = 0; ni < 4; ni++)
            bf[ni] = *(const short8_t*)&Bs_b[offB[ni]];
#pragma unroll
        for (int mi = 0; mi < 4; mi++)
#pragma unroll
            for (int ni = 0; ni < 4; ni++)
                acc[mi][ni] = __builtin_amdgcn_mfma_f32_16x16x32_bf16(
                    af[mi], bf[ni], acc[mi][ni], 0, 0, 0);
        asm volatile("s_barrier" ::: "memory");
    }
#undef STAGE

    // ---- epilogue: bias+relu, LDS-staged coalesced bf16 stores (2 rounds) ----
    short* St = smem;

    float bv[4];
#pragma unroll
    for (int ni = 0; ni < 4; ni++)
        bv[ni] = bias[n0 + wc * 64 + ni * 16 + r];

#pragma unroll
    for (int mp = 0; mp < 2; mp++) {
#pragma unroll
        for (int s = 0; s < 2; s++) {
#pragma unroll
            for (int ni = 0; ni < 4; ni++) {
#pragma unroll
                for (int e = 0; e < 4; e++) {
                    const int rl = s * 32 + wr * 16 + q * 4 + e;
                    const int col = wc * 64 + ni * 16 + r;
                    St[rl * 136 + col] =
                        f2bf(fmaxf(acc[mp * 2 + s][ni][e] + bv[ni], 0.f));
                }
            }
        }
        __syncthreads();
#pragma unroll
        for (int j = 0; j < 4; j++) {
            const int id = t + 256 * j;
            const int rl2 = id >> 4;
            const int ch = id & 15;
            const int s = rl2 >> 5;
            const int rl = rl2 & 31;
            const int grow = m0 + (rl >> 4) * 64 + (mp * 2 + s) * 16 + (rl & 15);
            const short8_t v = *(const short8_t*)&St[rl2 * 136 + ch * 8];
            if (grow < M)
                *(short8_t*)&Y[(size_t)grow * DIM + n0 + ch * 8] = v;
        }
        if (mp == 0) __syncthreads();
    }
}

// -------- aggregate over one rel-group, half-wave per dst, fp64 sums --------
// PHASE 0 (g0): acc[d][:] = (float)sum  (write-only).
// PHASE 1 (g1): out[d][:] = acc[d][:] + sum  (OT = bf16 h1b or f32 out).
// Deterministic: fp64 per-dst sums (order-free, R11) + fixed g0->g1 order.
// rel' = et & 3 (group base removed); yg = 4-plane buffer (L3-hot from the
// immediately preceding GEMM pass -- the whole point of R14).
template <int PHASE, typename OT>
__global__ __launch_bounds__(256) void aggregate_half(
    const unsigned short* __restrict__ yg,     // [4][M][256]
    const unsigned* __restrict__ ep, const int* __restrict__ rowptr, // +g*M
    float* __restrict__ acc, OT* __restrict__ out, int M)
{
    const int lane = threadIdx.x & 63;
    const int half = lane >> 5;     // which dst of the pair
    const int cl = lane & 31;       // 16B chunk within message row
    const int wv = (blockIdx.x * blockDim.x + threadIdx.x) >> 6;
    const int nw = (gridDim.x * blockDim.x) >> 6;
    const size_t plane = (size_t)M * DIM;
    const int npair = (M + 1) >> 1;

    for (int pr = wv; pr < npair; pr += nw) {
        const int d = 2 * pr + half;
        const bool live = (d < M);
        double s[8];
#pragma unroll
        for (int j = 0; j < 8; j++) s[j] = 0.0;

        int beg = 0, end = 0;
        if (live) { beg = rowptr[d]; end = rowptr[d + 1]; }

        for (int c0 = beg; c0 < end; c0 += 32) {
            const int n = min(32, end - c0);
            const unsigned myep = (c0 + cl < end) ? ep[c0 + cl] : 0u;
            for (int i = 0; i < n; i += 4) {
                short8_t u[4];
#pragma unroll
                for (int j = 0; j < 4; j++) {
                    const unsigned p = __shfl(myep, half * 32 + ((i + j) & 31));
                    u[j] = *(const short8_t*)(
                        yg + (size_t)((p >> 16) & 3) * plane +
                        (size_t)(p & 0xFFFFu) * DIM + cl * 8);
                }
#pragma unroll
                for (int j = 0; j < 4; j++) {
                    if (i + j < n) {
#pragma unroll
                        for (int k = 0; k < 8; k++)
                            s[k] += (double)bf2f((unsigned short)u[j][k]);
                    }
                }
            }
        }
        if (live) {
            float* ar = acc + (size_t)d * DIM + cl * 8;
            if (PHASE == 0) {
                *(float4*)ar = make_float4(
                    (float)s[0], (float)s[1], (float)s[2], (float)s[3]);
                *((float4*)ar + 1) = make_float4(
                    (float)s[4], (float)s[5], (float)s[6], (float)s[7]);
            } else {
                const float4 a0 = *(const float4*)ar;
                const float4 a1 = *((const float4*)ar + 1);
                float tot[8];
                tot[0] = a0.x + (float)s[0]; tot[1] = a0.y + (float)s[1];
                tot[2] = a0.z + (float)s[2]; tot[3] = a0.w + (float)s[3];
                tot[4] = a1.x + (float)s[4]; tot[5] = a1.y + (float)s[5];
                tot[6] = a1.z + (float)s[6]; tot[7] = a1.w + (float)s[7];
                OT* dp = out + (size_t)d * DIM + cl * 8;
                if (sizeof(OT) == 4) {
                    *(float4*)((float*)dp) = make_float4(tot[0], tot[1], tot[2], tot[3]);
                    *(float4*)((float*)dp + 4) = make_float4(tot[4], tot[5], tot[6], tot[7]);
                } else {
                    short8_t v;
#pragma unroll
                    for (int j = 0; j < 8; j++) v[j] = (short)f2bf(tot[j]);
                    *(short8_t*)((unsigned short*)dp) = v;
                }
            }
        }
    }
}

// ---------------- fallback: fp32 vector GEMM + atomic scatter ----------------
__global__ __launch_bounds__(256) void gemm_bias_relu_f32(
    const float* __restrict__ A, const float* __restrict__ B,
    const float* __restrict__ bias, float* __restrict__ Y, int M)
{
    __shared__ float Asf[16][132];
    __shared__ float Bsf[16][128];
    const int t = threadIdx.x;
    const int tx = t & 15, ty = t >> 4;
    const int row0 = blockIdx.x * 128, col0 = blockIdx.y * 128;
    float acc[8][8];
#pragma unroll
    for (int i = 0; i < 8; i++)
#pragma unroll
        for (int j = 0; j < 8; j++) acc[i][j] = 0.f;
    const int arow = t >> 2, akseg = (t & 3) * 4;
    const int bk0 = t >> 5, bcol = (t & 31) * 4;
    for (int k0 = 0; k0 < DIM; k0 += 16) {
#pragma unroll
        for (int h = 0; h < 2; h++) {
            const int row = row0 + arow + h * 64;
            float4 av = (row < M) ? *(const float4*)(A + (size_t)row * DIM + k0 + akseg)
                                  : make_float4(0, 0, 0, 0);
            Asf[akseg + 0][arow + h * 64] = av.x;
            Asf[akseg + 1][arow + h * 64] = av.y;
            Asf[akseg + 2][arow + h * 64] = av.z;
            Asf[akseg + 3][arow + h * 64] = av.w;
        }
#pragma unroll
        for (int h = 0; h < 2; h++) {
            const int krow = bk0 + h * 8;
            *(float4*)&Bsf[krow][bcol] =
                *(const float4*)(B + (size_t)(k0 + krow) * DIM + col0 + bcol);
        }
        __syncthreads();
#pragma unroll
        for (int k = 0; k < 16; k++) {
            float a[8], b[8];
            *(float4*)&a[0] = *(const float4*)&Asf[k][ty * 4];
            *(float4*)&a[4] = *(const float4*)&Asf[k][64 + ty * 4];
            *(float4*)&b[0] = *(const float4*)&Bsf[k][tx * 4];
            *(float4*)&b[4] = *(const float4*)&Bsf[k][64 + tx * 4];
#pragma unroll
            for (int i = 0; i < 8; i++)
#pragma unroll
                for (int j = 0; j < 8; j++) acc[i][j] = fmaf(a[i], b[j], acc[i][j]);
        }
        __syncthreads();
    }
#pragma unroll
    for (int im = 0; im < 2; im++)
#pragma unroll
        for (int i = 0; i < 4; i++) {
            const int row = row0 + im * 64 + ty * 4 + i;
            if (row >= M) continue;
#pragma unroll
            for (int jm = 0; jm < 2; jm++) {
                const int col = col0 + jm * 64 + tx * 4;
                const float4 bb = *(const float4*)(bias + col);
                float4 o;
                o.x = fmaxf(acc[im * 4 + i][jm * 4 + 0] + bb.x, 0.f);
                o.y = fmaxf(acc[im * 4 + i][jm * 4 + 1] + bb.y, 0.f);
                o.z = fmaxf(acc[im * 4 + i][jm * 4 + 2] + bb.z, 0.f);
                o.w = fmaxf(acc[im * 4 + i][jm * 4 + 3] + bb.w, 0.f);
                *(float4*)(Y + (size_t)row * DIM + col) = o;
            }
        }
}

__global__ __launch_bounds__(256) void scatter_rel(
    const float* __restrict__ y, const int* __restrict__ src,
    const int* __restrict__ dst, const int* __restrict__ et,
    int rel, float* __restrict__ out, int n_edges)
{
    const int lane = threadIdx.x & 63;
    const int wave = (blockIdx.x * blockDim.x + threadIdx.x) >> 6;
    const int nwaves = (gridDim.x * blockDim.x) >> 6;
    for (int e = wave; e < n_edges; e += nwaves) {
        if (et[e] != rel) continue;
        const float4 v = *(const float4*)(y + (size_t)src[e] * DIM + lane * 4);
        float* o = out + (size_t)dst[e] * DIM + lane * 4;
        atomicAdd(o + 0, v.x);
        atomicAdd(o + 1, v.y);
        atomicAdd(o + 2, v.z);
        atomicAdd(o + 3, v.w);
    }
}

static inline size_t align16(size_t x) { return (x + 15) & ~(size_t)15; }

extern "C" void kernel_launch(void* const* d_in, const int* in_sizes, int n_in,
                              void* d_out, int out_size, void* d_ws, size_t ws_size,
                              hipStream_t stream)
{
    const float* x  = (const float*)d_in[0];
    const float* W0 = (const float*)d_in[1];
    const float* b0 = (const float*)d_in[2];
    const float* W1 = (const float*)d_in[3];
    const float* b1 = (const float*)d_in[4];
    const int* eidx = (const int*)d_in[5];
    const int* etyp = (const int*)d_in[6];

    const int M = in_sizes[0] / DIM;   // 50000
    const int E = in_sizes[6];         // 800000
    const int* src = eidx;
    const int* dst = eidx + E;
    float* out = (float*)d_out;

    const size_t plane = (size_t)M * DIM;
    const size_t wbytes = (size_t)N_REL * DIM * DIM * 2;
    const size_t ybuf_bytes = (size_t)4 * plane * 2;       // 102.4MB (4 planes)

    const size_t need = align16(plane * 2)                 // h1b
                      + align16(plane * 2)                 // xb
                      + 2 * align16(wbytes)                // Wt0b, Wt1b
                      + align16((size_t)(2 * M + 1) * 4)   // rowptr2 [2M+1]
                      + align16((size_t)2 * M * 4)         // cnt2 [2M]
                      + align16((size_t)256 * 4)           // bsum
                      + align16((size_t)NBINS * NBLK * 4)  // hist (512KB)
                      + align16((size_t)E * 4)             // ep
                      + align16(plane * 4)                 // acc f32 (51.2MB)
                      + align16(ybuf_bytes);               // ybuf (e64 alias)

    if (M < 65536 && ws_size >= need && ybuf_bytes >= 2 * (size_t)E * 8) {
        char* ws = (char*)d_ws;
        size_t off = 0;
        unsigned short* h1b  = (unsigned short*)(ws + off); off = align16(off + plane * 2);
        unsigned short* xb   = (unsigned short*)(ws + off); off = align16(off + plane * 2);
        unsigned short* Wt0b = (unsigned short*)(ws + off); off = align16(off + wbytes);
        unsigned short* Wt1b = (unsigned short*)(ws + off); off = align16(off + wbytes);
        int* rowptr2 = (int*)(ws + off); off = align16(off + (size_t)(2 * M + 1) * 4);
        int* cnt2    = (int*)(ws + off); off = align16(off + (size_t)2 * M * 4);
        int* bsum    = (int*)(ws + off); off = align16(off + (size_t)256 * 4);
        int* hist    = (int*)(ws + off); off = align16(off + (size_t)NBINS * NBLK * 4);
        unsigned* ep = (unsigned*)(ws + off); off = align16(off + (size_t)E * 4);
        float* acc   = (float*)(ws + off); off = align16(off + plane * 4);
        unsigned short* ybuf = (unsigned short*)(ws + off);
        unsigned long long* e64a = (unsigned long long*)ybuf;   // transient
        unsigned long long* e64b = e64a + E;                    // transient

        // --- prep: cast + 2 transposes
        const int n4 = (int)(plane / 4);
        const int nCast = (n4 + 255) / 256;
        const int nW = 512;
        prep_mega<<<nCast + 2 * nW, 256, 0, stream>>>(
            x, xb, n4, W0, Wt0b, W1, Wt1b, nCast, nW);

        // --- atomic-free CSR build sorted by (g, dst)
        hipMemsetAsync(cnt2, 0, (size_t)2 * M * 4, stream);
        build_keys_hist<<<NBLK, 256, 0, stream>>>(src, dst, etyp, E, e64a, hist);
        const int nhist = NBINS * NBLK;                    // 131072
        const int nbh = (nhist + 1023) / 1024;             // 128
        scan_g_blocksums<<<nbh, 256, 0, stream>>>(hist, nhist, bsum);
        scan_g_write<<<nbh, 256, 0, stream>>>(hist, nhist, bsum, nbh, hist, (int*)nullptr);
        scatter_pass1<<<NBLK, 256, 0, stream>>>(e64a, E, hist, e64b);
        bucket_sort<<<NBINS, 256, 0, stream>>>(e64b, E, hist, ep, cnt2, M);
        const int n2m = 2 * M;
        const int nb2 = (n2m + 1023) / 1024;               // 98
        scan_g_blocksums<<<nb2, 256, 0, stream>>>(cnt2, n2m, bsum);
        scan_g_write<<<nb2, 256, 0, stream>>>(cnt2, n2m, bsum, nb2, rowptr2, &rowptr2[n2m]);

        const int Rtiles = (M + 127) / 128;
        const int octets = (Rtiles + 7) / 8;
        const int ggrid = octets * 8 * 8;                  // 8 combos (4 rels)
        const int npair = (M + 1) / 2;
        const int agrid = (npair * 64 + 255) / 256;        // 1 dst per half-wave
        const size_t wgrp = (size_t)4 * DIM * DIM;         // 4 planes of W (shorts)

        // layer 1: g0 GEMM -> g0 aggregate (ybuf L3-hot) -> g1 GEMM -> g1 agg
        gemm_mfma_bias_relu<<<ggrid, 256, 0, stream>>>(xb, Wt0b, b0, ybuf, M, Rtiles);
        aggregate_half<0, unsigned short><<<agrid, 256, 0, stream>>>(
            ybuf, ep, rowptr2, acc, h1b, M);
        gemm_mfma_bias_relu<<<ggrid, 256, 0, stream>>>(xb, Wt0b + wgrp, b0, ybuf, M, Rtiles);
        aggregate_half<1, unsigned short><<<agrid, 256, 0, stream>>>(
            ybuf, ep, rowptr2 + M, acc, h1b, M);
        // layer 2
        gemm_mfma_bias_relu<<<ggrid, 256, 0, stream>>>(h1b, Wt1b, b1, ybuf, M, Rtiles);
        aggregate_half<0, float><<<agrid, 256, 0, stream>>>(
            ybuf, ep, rowptr2, acc, out, M);
        gemm_mfma_bias_relu<<<ggrid, 256, 0, stream>>>(h1b, Wt1b + wgrp, b1, ybuf, M, Rtiles);
        aggregate_half<1, float><<<agrid, 256, 0, stream>>>(
            ybuf, ep, rowptr2 + M, acc, out, M);
    } else {
        // fallback: fp32 per-relation GEMM + atomic scatter
        float* h1 = (float*)d_ws;
        float* y  = (float*)d_ws + plane;
        const dim3 gblk(256), ggrid2((M + 127) / 128, DIM / 128);
        hipMemsetAsync(h1, 0, plane * 4, stream);
        for (int r = 0; r < N_REL; r++) {
            gemm_bias_relu_f32<<<ggrid2, gblk, 0, stream>>>(
                x, W0 + (size_t)r * DIM * DIM, b0, y, M);
            scatter_rel<<<1024, 256, 0, stream>>>(y, src, dst, etyp, r, h1, E);
        }
        hipMemsetAsync(out, 0, plane * 4, stream);
        for (int r = 0; r < N_REL; r++) {
            gemm_bias_relu_f32<<<ggrid2, gblk, 0, stream>>>(
                h1, W1 + (size_t)r * DIM * DIM, b1, y, M);
            scatter_rel<<<1024, 256, 0, stream>>>(y, src, dst, etyp, r, out, E);
        }
    }
}